// Round 17
// baseline (196.766 us; speedup 1.0000x reference)
//
#include <hip/hip_runtime.h>

// NarrativeClassificationLoss — v19: 2-dispatch (last-block reduce+fin).
// R16 post-mortem of v18 (72us, VGPR 56, WRITE clean): the asm batch DID
// force 8-deep VMEM (results live -> 56 VGPR) and perf got WORSE — the
// burst+vmcnt(0) drain removed natural cross-wave staggering. Per the
// R15 pre-commitment, per-wave request depth is FALSIFIED. Elimination
// matrix complete: occupancy 11-46%, fetch 74-96MB, MLP 1-8 deep, DMA
// staging, atomics, slices, spills, grid/block shape — all non-levers.
// Main-kernel plateau ~63us (=2.3TB/s logical) is this op's service
// rate on this compiler/harness. Main reverts to v12 (best clean).
// Remaining lever: dispatch count. total-main ~115us incl ~8us/launch.
// v19 fuses reduce1+finalize via the LAST-BLOCK pattern (cooperative
// launch no-ops under graph capture, R10): ncl_main zeroes a ws counter
// (kernel boundary = visibility); 224 reduce blocks threadfence +
// atomicAdd; the last block re-reads the 16 L2-hot group tables (221KB)
// and finalizes. 224 end-of-kernel atomics ~= nothing (v6's lesson was
// 890K hot-path atomics). 2 dispatches, no memset.
//
// B=16384, N_NARR=128, N_SUB=1024, K=8, GAMMA=2, weights (1,1,0.5).

#define BDIM 256
#define NROWS 16384
#define NNARR 128
#define NSUB 1024
#define RPB 16
#define NBLOCKS (NROWS / RPB)              // 1024

// per-block table layout (floats)
#define WS_AN    0      // [128]  sum_b y*sp(-x)            (narrative)
#define WS_CN    128    // [128]  sum_b (1-y)*sp(x)
#define WS_NSUM  256    // [128]  col sums of narrative labels
#define WS_AS    384    // [1024] sum_b pos*y*sp(-x)        (subnarrative)
#define WS_CS    1408   // [1024] sum_b pos*(1-y)*sp(x)
#define WS_SSUM  2432   // [1024] col sums of sub labels
#define WS_FN    3456   // focal narrative sum
#define WS_FS    3457   // focal subnarrative sum
#define WS_HIER  3458   // hierarchy sum
#define WS_FLOATS 3459
#define CSTRIDE  3472   // table stride in floats (16B aligned)

#define NCHUNK 16                          // reduce fan-in groups
#define TPG (NBLOCKS / NCHUNK)             // 64 tables per group
#define ECH ((WS_FLOATS + 255) / 256)      // 14 element chunks
#define NRBLOCKS (ECH * NCHUNK)            // 224 reduce blocks

__device__ __forceinline__ void bce_pieces(float x, float& sp_p, float& sp_m, float& sig) {
    float a = fabsf(x);
    float e = __expf(-a);              // exp(-|x|) in (0,1]
    float l = __logf(1.0f + e);        // ~log1p(e); err ~1e-7, fine after /2M
    sp_p = fmaxf(x, 0.0f) + l;
    sp_m = sp_p - x;
    float inv = __builtin_amdgcn_rcpf(1.0f + e);
    sig = (x >= 0.0f) ? inv : e * inv;
}

__global__ void __launch_bounds__(BDIM)
__attribute__((amdgpu_waves_per_eu(4, 4)))
ncl_main(
    const float* __restrict__ nlog, const float* __restrict__ slog,
    const int*   __restrict__ nlab, const int*   __restrict__ slab,
    float* __restrict__ P, int* __restrict__ counter)
{
    __shared__ float ssc[4][3];        // per-wave scalar partials

    const int t  = threadIdx.x;
    const int g  = t >> 1;
    const int r0 = blockIdx.x * RPB;
    float* const Pb = P + (size_t)blockIdx.x * CSTRIDE;

    // zero the completion counter for the reduce kernel (stream order
    // + kernel boundary guarantee visibility before any reduce block).
    if (blockIdx.x == 0 && t == 0) *counter = 0;

    float As[4] = {0,0,0,0}, Cs[4] = {0,0,0,0}, ss[4] = {0,0,0,0};
    float An = 0.f, Cn = 0.f, ns = 0.f, fn = 0.f, fs = 0.f, hier = 0.f;

    const float* sp = slog + (size_t)r0 * NSUB + 4 * t;
    const int*   lp = slab + (size_t)r0 * NSUB + 4 * t;
    const float* np = nlog + (size_t)r0 * NNARR + g;
    const int*   mp = nlab + (size_t)r0 * NNARR + g;

    #pragma unroll 2
    for (int i = 0; i < RPB; ++i) {
        const float4 xs   = *(const float4*)(sp + (size_t)i * NSUB);
        const int4   ys   = *(const int4*)  (lp + (size_t)i * NSUB);
        const float  nx   = np[(size_t)i * NNARR];
        const float  posv = (float)mp[(size_t)i * NNARR];   // narr label == pos mask

        float nsp_p, nsp_m, nsig;
        bce_pieces(nx, nsp_p, nsp_m, nsig);

        const float xv[4] = {xs.x, xs.y, xs.z, xs.w};
        const float yv[4] = {(float)ys.x, (float)ys.y, (float)ys.z, (float)ys.w};
        float mymax = 0.0f;
        #pragma unroll
        for (int k = 0; k < 4; ++k) {
            float sp_p, sp_m, sig;
            bce_pieces(xv[k], sp_p, sp_m, sig);
            float y = yv[k];
            As[k] += posv * y * sp_m;
            Cs[k] += posv * (1.0f - y) * sp_p;
            ss[k] += y;
            float om = 1.0f - sig;
            fs += om * om * y * (-sp_m);     // log_sigmoid(x) = -softplus(-x)
            mymax = fmaxf(mymax, sig);
        }
        // group of 8 sub cols = adjacent lane pair (t, t^1): same narr col
        float gmax = fmaxf(mymax, __shfl_xor(mymax, 1, 64));
        if ((t & 1) == 0) {
            hier += fmaxf(gmax - nsig, 0.0f) * posv;
            An += posv * nsp_m;
            Cn += (1.0f - posv) * nsp_p;
            ns += posv;
            float om = 1.0f - nsig;
            fn += om * om * posv * (-nsp_m);
        }
    }

    // exclusive per-block table: plain stores, no atomics.
    *(float4*)(Pb + WS_AS   + 4 * t) = make_float4(As[0], As[1], As[2], As[3]);
    *(float4*)(Pb + WS_CS   + 4 * t) = make_float4(Cs[0], Cs[1], Cs[2], Cs[3]);
    *(float4*)(Pb + WS_SSUM + 4 * t) = make_float4(ss[0], ss[1], ss[2], ss[3]);
    if ((t & 1) == 0) {
        Pb[WS_AN   + g] = An;
        Pb[WS_CN   + g] = Cn;
        Pb[WS_NSUM + g] = ns;
    }

    // scalar partials: wave shuffle reduce -> LDS -> thread 0
    #pragma unroll
    for (int off = 32; off; off >>= 1) {
        fn   += __shfl_down(fn,   off, 64);
        fs   += __shfl_down(fs,   off, 64);
        hier += __shfl_down(hier, off, 64);
    }
    if ((t & 63) == 0) {
        int w = t >> 6;
        ssc[w][0] = fn; ssc[w][1] = fs; ssc[w][2] = hier;
    }
    __syncthreads();
    if (t == 0) {
        float a = 0.f, b = 0.f, c = 0.f;
        #pragma unroll
        for (int w = 0; w < 4; ++w) { a += ssc[w][0]; b += ssc[w][1]; c += ssc[w][2]; }
        Pb[WS_FN] = a; Pb[WS_FS] = b; Pb[WS_HIER] = c;
    }
}

// fused reduce + finalize. Grid (ECH, NCHUNK) = 224 blocks x 256 thr.
// Each block reduces its (element-chunk, group) over 64 tables -> tmp;
// the LAST block (atomic counter) re-reads the 16 group tables (221KB,
// L2-hot) and finalizes. Zero extra dispatches.
__global__ __launch_bounds__(256) void ncl_reduce_fin(
    const float* __restrict__ P, float* __restrict__ tmp,
    int* __restrict__ counter, float* __restrict__ out)
{
    __shared__ float sr[6][4];
    __shared__ int lastv;

    const int t  = threadIdx.x;
    const int ec = blockIdx.x;         // element chunk 0..13
    const int gg = blockIdx.y;         // group 0..15
    const int e  = ec * 256 + t;

    if (e < WS_FLOATS) {
        const float* p = P + (size_t)gg * TPG * CSTRIDE + e;
        float s = 0.f;
        #pragma unroll 4
        for (int i = 0; i < TPG; ++i)
            s += p[(size_t)i * CSTRIDE];
        tmp[(size_t)gg * CSTRIDE + e] = s;
    }

    // completion protocol: make tmp writes device-visible, then count.
    __threadfence();
    __syncthreads();
    if (t == 0)
        lastv = (atomicAdd(counter, 1) == NRBLOCKS - 1) ? 1 : 0;
    __syncthreads();
    if (!lastv) return;
    __threadfence();   // acquire: all other blocks' tmp writes visible

    // ---- finalize, 256 threads (last block only) ----
    const float Bf = (float)NROWS;

    // sub columns: thread t owns cols {t, t+256, t+512, t+768}
    float sub_part = 0.f;
    #pragma unroll
    for (int cc = 0; cc < 4; ++cc) {
        const int c = cc * 256 + t;
        float As = 0.f, Csv = 0.f, sv = 0.f;
        #pragma unroll
        for (int g2 = 0; g2 < NCHUNK; ++g2) {
            const float* p = tmp + (size_t)g2 * CSTRIDE;
            As  += p[WS_AS   + c];
            Csv += p[WS_CS   + c];
            sv  += p[WS_SSUM + c];
        }
        float spw = fminf(fmaxf((Bf - sv) / (sv + 1e-6f), 1.0f), 50.0f);
        sub_part += spw * As + Csv;
    }

    float narr_part = 0.f, valid_part = 0.f;
    if (t < NNARR) {
        float An = 0.f, Cn = 0.f, ns = 0.f;
        #pragma unroll
        for (int g2 = 0; g2 < NCHUNK; ++g2) {
            const float* p = tmp + (size_t)g2 * CSTRIDE;
            An += p[WS_AN + t]; Cn += p[WS_CN + t]; ns += p[WS_NSUM + t];
        }
        float npw = fminf(fmaxf((Bf - ns) / (ns + 1e-6f), 1.0f), 50.0f);
        narr_part  = npw * An + Cn;
        valid_part = ns;
    }

    float fn_p = 0.f, fs_p = 0.f, hier_p = 0.f;
    if (t < NCHUNK) {
        const float* p = tmp + (size_t)t * CSTRIDE;
        fn_p = p[WS_FN]; fs_p = p[WS_FS]; hier_p = p[WS_HIER];
    }

    #pragma unroll
    for (int off = 32; off; off >>= 1) {
        sub_part   += __shfl_down(sub_part,   off, 64);
        narr_part  += __shfl_down(narr_part,  off, 64);
        valid_part += __shfl_down(valid_part, off, 64);
        fn_p       += __shfl_down(fn_p,       off, 64);
        fs_p       += __shfl_down(fs_p,       off, 64);
        hier_p     += __shfl_down(hier_p,     off, 64);
    }
    if ((t & 63) == 0) {
        int w = t >> 6;
        sr[0][w] = sub_part; sr[1][w] = narr_part; sr[2][w] = valid_part;
        sr[3][w] = fn_p;     sr[4][w] = fs_p;      sr[5][w] = hier_p;
    }
    __syncthreads();
    if (t == 0) {
        float sub_tot = 0.f, narr_tot = 0.f, valid = 0.f;
        float fn = 0.f, fs = 0.f, hier = 0.f;
        #pragma unroll
        for (int i = 0; i < 4; ++i) {
            sub_tot += sr[0][i]; narr_tot += sr[1][i]; valid += sr[2][i];
            fn += sr[3][i]; fs += sr[4][i]; hier += sr[5][i];
        }

        float narrative_loss = narr_tot / (Bf * (float)NNARR);
        float sub_loss = (valid > 0.0f) ? (sub_tot * (1.0f / 8.0f)) / fmaxf(valid, 1.0f) : 0.0f;
        float nf = fn / (Bf * (float)NNARR);
        float sf = fs / (Bf * (float)NSUB);
        float hier_loss = hier / Bf;

        out[0] = (narrative_loss - 0.1f * nf)
               + (sub_loss       - 0.1f * sf)
               + 0.5f * hier_loss;
    }
}

extern "C" void kernel_launch(void* const* d_in, const int* in_sizes, int n_in,
                              void* d_out, int out_size, void* d_ws, size_t ws_size,
                              hipStream_t stream) {
    const float* nlog = (const float*)d_in[0];
    const float* slog = (const float*)d_in[1];
    const int*   nlab = (const int*)d_in[2];
    const int*   slab = (const int*)d_in[3];
    float* P   = (float*)d_ws;                        // 1024 tables
    float* tmp = P + (size_t)NBLOCKS * CSTRIDE;       // 16 group tables
    int*   counter = (int*)(tmp + (size_t)NCHUNK * CSTRIDE);
    float* out = (float*)d_out;

    // ncl_main zeroes the counter; all other ws cells are exclusively
    // written before read: no memset, 2 dispatches total.
    ncl_main<<<NBLOCKS, BDIM, 0, stream>>>(nlog, slog, nlab, slab, P, counter);
    dim3 gr(ECH, NCHUNK);
    ncl_reduce_fin<<<gr, 256, 0, stream>>>(P, tmp, counter, out);
}

// Round 18
// 183.587 us; speedup vs baseline: 1.0718x; 1.0718x over previous
//
#include <hip/hip_runtime.h>

// NarrativeClassificationLoss — v20 (FINAL): revert to v12, the best
// clean variant (181.6us total, main 63-65us, VGPR 52, zero spill).
// R17 post-mortem of v19 (196.8us): dispatch fusion FALSIFIED — the
// 2-dispatch last-block protocol added tail latency; totals across
// 2/3/5-dispatch structures all land 180-197us => total-main ~115us is
// FIXED harness overhead, not per-dispatch cost.
// Elimination matrix closed over 17 rounds — main pinned at 63-66us
// across: occupancy 11-46%, fetch 74-96MB, grid 1024-2048, MLP depth
// 1-8 (source-batch, sched_barrier, inline-asm forced), LDS DMA staging,
// column slices, atomics vs exclusive stores, spills, dispatch count.
// The ~2.2-2.5 TB/s logical service rate (VALU 28%, HBM 18%) is this
// op's structural limit on this compiler/harness. This is the roofline.
//
// Keeper structure: fused single-pass main (narrative accumulators fold
// into the sub loop on even lanes — no separate narrative phase), zero
// atomics, exclusive per-block tables, amdgpu_waves_per_eu(4,4) (128-
// VGPR budget, kills the max-occupancy spill heuristic), coalesced
// 16-group reduce + 1-block finalize. 3 dispatches, no memset.
//
// B=16384, N_NARR=128, N_SUB=1024, K=8, GAMMA=2, weights (1,1,0.5).

#define BDIM 256
#define NROWS 16384
#define NNARR 128
#define NSUB 1024
#define RPB 16
#define NBLOCKS (NROWS / RPB)              // 1024

// per-block table layout (floats)
#define WS_AN    0      // [128]  sum_b y*sp(-x)            (narrative)
#define WS_CN    128    // [128]  sum_b (1-y)*sp(x)
#define WS_NSUM  256    // [128]  col sums of narrative labels
#define WS_AS    384    // [1024] sum_b pos*y*sp(-x)        (subnarrative)
#define WS_CS    1408   // [1024] sum_b pos*(1-y)*sp(x)
#define WS_SSUM  2432   // [1024] col sums of sub labels
#define WS_FN    3456   // focal narrative sum
#define WS_FS    3457   // focal subnarrative sum
#define WS_HIER  3458   // hierarchy sum
#define WS_FLOATS 3459
#define CSTRIDE  3472   // table stride in floats (16B aligned)

#define NCHUNK 16                          // reduce fan-in groups
#define TPG (NBLOCKS / NCHUNK)             // 64 tables per group

__device__ __forceinline__ void bce_pieces(float x, float& sp_p, float& sp_m, float& sig) {
    float a = fabsf(x);
    float e = __expf(-a);              // exp(-|x|) in (0,1]
    float l = __logf(1.0f + e);        // ~log1p(e); err ~1e-7, fine after /2M
    sp_p = fmaxf(x, 0.0f) + l;
    sp_m = sp_p - x;
    float inv = __builtin_amdgcn_rcpf(1.0f + e);
    sig = (x >= 0.0f) ? inv : e * inv;
}

__global__ void __launch_bounds__(BDIM)
__attribute__((amdgpu_waves_per_eu(4, 4)))
ncl_main(
    const float* __restrict__ nlog, const float* __restrict__ slog,
    const int*   __restrict__ nlab, const int*   __restrict__ slab,
    float* __restrict__ P)
{
    __shared__ float ssc[4][3];        // per-wave scalar partials

    const int t  = threadIdx.x;
    const int g  = t >> 1;
    const int r0 = blockIdx.x * RPB;
    float* const Pb = P + (size_t)blockIdx.x * CSTRIDE;

    float As[4] = {0,0,0,0}, Cs[4] = {0,0,0,0}, ss[4] = {0,0,0,0};
    float An = 0.f, Cn = 0.f, ns = 0.f, fn = 0.f, fs = 0.f, hier = 0.f;

    const float* sp = slog + (size_t)r0 * NSUB + 4 * t;
    const int*   lp = slab + (size_t)r0 * NSUB + 4 * t;
    const float* np = nlog + (size_t)r0 * NNARR + g;
    const int*   mp = nlab + (size_t)r0 * NNARR + g;

    #pragma unroll 2
    for (int i = 0; i < RPB; ++i) {
        const float4 xs   = *(const float4*)(sp + (size_t)i * NSUB);
        const int4   ys   = *(const int4*)  (lp + (size_t)i * NSUB);
        const float  nx   = np[(size_t)i * NNARR];
        const float  posv = (float)mp[(size_t)i * NNARR];   // narr label == pos mask

        float nsp_p, nsp_m, nsig;
        bce_pieces(nx, nsp_p, nsp_m, nsig);

        const float xv[4] = {xs.x, xs.y, xs.z, xs.w};
        const float yv[4] = {(float)ys.x, (float)ys.y, (float)ys.z, (float)ys.w};
        float mymax = 0.0f;
        #pragma unroll
        for (int k = 0; k < 4; ++k) {
            float sp_p, sp_m, sig;
            bce_pieces(xv[k], sp_p, sp_m, sig);
            float y = yv[k];
            As[k] += posv * y * sp_m;
            Cs[k] += posv * (1.0f - y) * sp_p;
            ss[k] += y;
            float om = 1.0f - sig;
            fs += om * om * y * (-sp_m);     // log_sigmoid(x) = -softplus(-x)
            mymax = fmaxf(mymax, sig);
        }
        // group of 8 sub cols = adjacent lane pair (t, t^1): same narr col
        float gmax = fmaxf(mymax, __shfl_xor(mymax, 1, 64));
        if ((t & 1) == 0) {
            hier += fmaxf(gmax - nsig, 0.0f) * posv;
            An += posv * nsp_m;
            Cn += (1.0f - posv) * nsp_p;
            ns += posv;
            float om = 1.0f - nsig;
            fn += om * om * posv * (-nsp_m);
        }
    }

    // exclusive per-block table: plain stores, no atomics.
    *(float4*)(Pb + WS_AS   + 4 * t) = make_float4(As[0], As[1], As[2], As[3]);
    *(float4*)(Pb + WS_CS   + 4 * t) = make_float4(Cs[0], Cs[1], Cs[2], Cs[3]);
    *(float4*)(Pb + WS_SSUM + 4 * t) = make_float4(ss[0], ss[1], ss[2], ss[3]);
    if ((t & 1) == 0) {
        Pb[WS_AN   + g] = An;
        Pb[WS_CN   + g] = Cn;
        Pb[WS_NSUM + g] = ns;
    }

    // scalar partials: wave shuffle reduce -> LDS -> thread 0
    #pragma unroll
    for (int off = 32; off; off >>= 1) {
        fn   += __shfl_down(fn,   off, 64);
        fs   += __shfl_down(fs,   off, 64);
        hier += __shfl_down(hier, off, 64);
    }
    if ((t & 63) == 0) {
        int w = t >> 6;
        ssc[w][0] = fn; ssc[w][1] = fs; ssc[w][2] = hier;
    }
    __syncthreads();
    if (t == 0) {
        float a = 0.f, b = 0.f, c = 0.f;
        #pragma unroll
        for (int w = 0; w < 4; ++w) { a += ssc[w][0]; b += ssc[w][1]; c += ssc[w][2]; }
        Pb[WS_FN] = a; Pb[WS_FS] = b; Pb[WS_HIER] = c;
    }
}

// reduce: block (e-chunk, g) sums TPG tables -> tmp[g]; fully coalesced.
__global__ __launch_bounds__(256) void ncl_reduce1(const float* __restrict__ P,
                                                   float* __restrict__ tmp)
{
    const int e = blockIdx.x * 256 + threadIdx.x;
    if (e >= WS_FLOATS) return;
    const int gg = blockIdx.y;
    const float* p = P + (size_t)gg * TPG * CSTRIDE + e;
    float s = 0.f;
    #pragma unroll 4
    for (int i = 0; i < TPG; ++i)
        s += p[(size_t)i * CSTRIDE];
    tmp[(size_t)gg * CSTRIDE + e] = s;
}

__global__ __launch_bounds__(1024) void ncl_finalize(const float* __restrict__ tmp,
                                                     float* __restrict__ out)
{
    __shared__ float sr[6][16];
    const int t = threadIdx.x;
    const float Bf = (float)NROWS;

    // sub column t, summed over the 16 chunk tables (coalesced across t)
    float As = 0.f, Csv = 0.f, ss = 0.f;
    #pragma unroll 4
    for (int gc = 0; gc < NCHUNK; ++gc) {
        const float* p = tmp + (size_t)gc * CSTRIDE;
        As  += p[WS_AS   + t];
        Csv += p[WS_CS   + t];
        ss  += p[WS_SSUM + t];
    }
    float spw = fminf(fmaxf((Bf - ss) / (ss + 1e-6f), 1.0f), 50.0f);
    float sub_part = spw * As + Csv;

    float narr_part = 0.f, valid_part = 0.f;
    if (t < NNARR) {
        float An = 0.f, Cn = 0.f, ns = 0.f;
        #pragma unroll 4
        for (int gc = 0; gc < NCHUNK; ++gc) {
            const float* p = tmp + (size_t)gc * CSTRIDE;
            An += p[WS_AN + t]; Cn += p[WS_CN + t]; ns += p[WS_NSUM + t];
        }
        float npw = fminf(fmaxf((Bf - ns) / (ns + 1e-6f), 1.0f), 50.0f);
        narr_part  = npw * An + Cn;
        valid_part = ns;
    }

    float fn_p = 0.f, fs_p = 0.f, hier_p = 0.f;
    if (t < NCHUNK) {
        const float* p = tmp + (size_t)t * CSTRIDE;
        fn_p = p[WS_FN]; fs_p = p[WS_FS]; hier_p = p[WS_HIER];
    }

    #pragma unroll
    for (int off = 32; off; off >>= 1) {
        sub_part   += __shfl_down(sub_part,   off, 64);
        narr_part  += __shfl_down(narr_part,  off, 64);
        valid_part += __shfl_down(valid_part, off, 64);
        fn_p       += __shfl_down(fn_p,       off, 64);
        fs_p       += __shfl_down(fs_p,       off, 64);
        hier_p     += __shfl_down(hier_p,     off, 64);
    }
    if ((t & 63) == 0) {
        int w = t >> 6;
        sr[0][w] = sub_part; sr[1][w] = narr_part; sr[2][w] = valid_part;
        sr[3][w] = fn_p;     sr[4][w] = fs_p;      sr[5][w] = hier_p;
    }
    __syncthreads();
    if (t == 0) {
        float sub_tot = 0.f, narr_tot = 0.f, valid = 0.f;
        float fn = 0.f, fs = 0.f, hier = 0.f;
        #pragma unroll
        for (int i = 0; i < 16; ++i) {
            sub_tot += sr[0][i]; narr_tot += sr[1][i]; valid += sr[2][i];
            fn += sr[3][i]; fs += sr[4][i]; hier += sr[5][i];
        }

        float narrative_loss = narr_tot / (Bf * (float)NNARR);
        float sub_loss = (valid > 0.0f) ? (sub_tot * (1.0f / 8.0f)) / fmaxf(valid, 1.0f) : 0.0f;
        float nf = fn / (Bf * (float)NNARR);
        float sf = fs / (Bf * (float)NSUB);
        float hier_loss = hier / Bf;

        out[0] = (narrative_loss - 0.1f * nf)
               + (sub_loss       - 0.1f * sf)
               + 0.5f * hier_loss;
    }
}

extern "C" void kernel_launch(void* const* d_in, const int* in_sizes, int n_in,
                              void* d_out, int out_size, void* d_ws, size_t ws_size,
                              hipStream_t stream) {
    const float* nlog = (const float*)d_in[0];
    const float* slog = (const float*)d_in[1];
    const int*   nlab = (const int*)d_in[2];
    const int*   slab = (const int*)d_in[3];
    float* P   = (float*)d_ws;                        // 1024 tables
    float* tmp = P + (size_t)NBLOCKS * CSTRIDE;       // 16 group tables
    float* out = (float*)d_out;

    // all workspace cells are exclusively written before read: no memset.
    ncl_main<<<NBLOCKS, BDIM, 0, stream>>>(nlog, slog, nlab, slab, P);
    dim3 gr((WS_FLOATS + 255) / 256, NCHUNK);
    ncl_reduce1<<<gr, 256, 0, stream>>>(P, tmp);
    ncl_finalize<<<1, 1024, 0, stream>>>(tmp, out);
}